// Round 2
// 77.313 us; speedup vs baseline: 1.0224x; 1.0224x over previous
//
#include <hip/hip_runtime.h>
#include <stdint.h>

#define IN_F   1024
#define OUT_F  512
#define BATCH  256

// ---------------------------------------------------------------------------
// Kernel A (UNCHANGED): per (o,i) decide EDGE (argmax idx 0) vs NO_EDGE, pack
// via ballot. Deinterleaved-by-4 layout so kernel B can use the bit-l == lane-l
// VCC trick while keeping float4 x loads:
//   mask_t[o*16 + c*4 + j], bit l  <=>  EDGE at i = c*256 + 4*l + j
// Emulates numpy's f32 op sequence exactly; f32 logs computed correctly-rounded
// via double log (HIP logf ~2 ulp flips near-tied argmax decisions vs numpy).
// EDGE predicate: !(t1 > t0)  (np.argmax tie -> first max = index 0 = edge).
// ---------------------------------------------------------------------------
__global__ __launch_bounds__(256) void mask_kernel(
    const float* __restrict__ etc,          // [OUT_F, IN_F, 2]
    const float* __restrict__ un,           // [OUT_F, IN_F, 2]
    unsigned long long* __restrict__ mask_t)// [OUT_F * 16]
{
    int o = blockIdx.x >> 2;
    int c = blockIdx.x & 3;
    int j = threadIdx.x >> 6;   // wave id = sub-position within float4
    int l = threadIdx.x & 63;   // lane = bit position
    int i = c * 256 + l * 4 + j;
    int p = o * IN_F + i;

    float2 e = ((const float2*)etc)[p];
    float2 u = ((const float2*)un)[p];

    float s0 = u.x + 1e-10f;
    float l0 = (float)log((double)s0);
    float m0 = -l0 + 1e-10f;
    float g0 = -(float)log((double)m0);
    float t0 = e.x + g0;

    float s1 = u.y + 1e-10f;
    float l1 = (float)log((double)s1);
    float m1 = -l1 + 1e-10f;
    float g1 = -(float)log((double)m1);
    float t1 = e.y + g1;

    unsigned long long bits = __ballot(!(t1 > t0));   // 1 = edge
    if (l == 0) mask_t[o * 16 + c * 4 + j] = bits;
}

// ---------------------------------------------------------------------------
// Kernel B: out[b,o] = reduce_i (edge ? x[b,i] : offset), acc init = offset.
//
// This round (issue-count cut, target ~-30% vs 79 us baseline):
//  * 2 b-rows per wave (masks are b-independent -> shared SGPR mask words,
//    halves wave count 32768->16384 and halves scalar mask-load traffic).
//  * v_min3_f32 / v_max3_f32 packing: per float4 per row, 4 csel + 2 min3
//    (6 VALU) instead of 4 csel + 4 min (8 VALU).
//  * pair-merged butterfly, BRANCHLESS: each lane exposes the value its
//    cross-half partner needs (cross = hi ? rowA : rowB), one full-wave
//    __shfl_xor(cross, 32), one select, one min/max -> low 32 lanes carry
//    row A, high 32 lanes row B; then a SINGLE 5-step xor-butterfly
//    (d=16..1, stays within each 32-lane half) finishes both reductions.
//    lane 0 holds out[b,o], lane 32 holds out[b+1,o].
// ---------------------------------------------------------------------------
__device__ __forceinline__ float csel(unsigned long long m, float xv, float sent) {
    // r = bit_lane(m) ? xv : sent   -- one v_cndmask_b32 (VOP3, sgpr-pair mask)
    float r;
    asm("v_cndmask_b32 %0, %1, %2, %3" : "=v"(r) : "v"(sent), "v"(xv), "s"(m));
    return r;
}
__device__ __forceinline__ float vmin3(float a, float b, float c) {
    float r;
    asm("v_min3_f32 %0, %1, %2, %3" : "=v"(r) : "v"(a), "v"(b), "v"(c));
    return r;
}
__device__ __forceinline__ float vmax3(float a, float b, float c) {
    float r;
    asm("v_max3_f32 %0, %1, %2, %3" : "=v"(r) : "v"(a), "v"(b), "v"(c));
    return r;
}

__global__ __launch_bounds__(256, 8) void reduce_kernel(
    const float* __restrict__ x,                   // [BATCH, IN_F]
    const unsigned long long* __restrict__ mask_t, // [OUT_F * 16]
    float* __restrict__ out)                       // [BATCH, OUT_F]
{
    int wave = threadIdx.x >> 6;
    int lane = threadIdx.x & 63;
    int T = blockIdx.x * 4 + wave;                     // 16384 wave-tasks
    int bp = __builtin_amdgcn_readfirstlane(T >> 7);   // b-pair index 0..127
    int r  = T & 127;
    int parity = __builtin_amdgcn_readfirstlane(r & 1);
    int oq = __builtin_amdgcn_readfirstlane(r >> 1);   // 0..63: group of 4 o's

    const float4* xA = (const float4*)(x + (bp * 2 + 0) * IN_F);
    const float4* xB = (const float4*)(x + (bp * 2 + 1) * IN_F);

    // the 4 output rows this wave computes: o_g = (oq*4+g)*2 + parity
    int o0 = ((oq * 4 + 0) << 1) | parity;
    int o1 = ((oq * 4 + 1) << 1) | parity;
    int o2 = ((oq * 4 + 2) << 1) | parity;
    int o3 = ((oq * 4 + 3) << 1) | parity;
    const unsigned long long* mw0 = mask_t + o0 * 16;
    const unsigned long long* mw1 = mask_t + o1 * 16;
    const unsigned long long* mw2 = mask_t + o2 * 16;
    const unsigned long long* mw3 = mask_t + o3 * 16;

    bool hi = (lane & 32) != 0;

    if (parity == 0) {
        // t-norm: min, offset/sentinel 2.0
        const float S = 2.0f;
        float aA0=S, aA1=S, aA2=S, aA3=S;
        float aB0=S, aB1=S, aB2=S, aB3=S;
        #pragma unroll
        for (int c = 0; c < 4; ++c) {
            float4 va = xA[c * 64 + lane];
            float4 vb = xB[c * 64 + lane];
            {
                unsigned long long m0=mw0[c*4+0], m1=mw0[c*4+1], m2=mw0[c*4+2], m3=mw0[c*4+3];
                aA0 = vmin3(aA0, vmin3(csel(m0,va.x,S), csel(m1,va.y,S), csel(m2,va.z,S)), csel(m3,va.w,S));
                aB0 = vmin3(aB0, vmin3(csel(m0,vb.x,S), csel(m1,vb.y,S), csel(m2,vb.z,S)), csel(m3,vb.w,S));
            }
            {
                unsigned long long m0=mw1[c*4+0], m1=mw1[c*4+1], m2=mw1[c*4+2], m3=mw1[c*4+3];
                aA1 = vmin3(aA1, vmin3(csel(m0,va.x,S), csel(m1,va.y,S), csel(m2,va.z,S)), csel(m3,va.w,S));
                aB1 = vmin3(aB1, vmin3(csel(m0,vb.x,S), csel(m1,vb.y,S), csel(m2,vb.z,S)), csel(m3,vb.w,S));
            }
            {
                unsigned long long m0=mw2[c*4+0], m1=mw2[c*4+1], m2=mw2[c*4+2], m3=mw2[c*4+3];
                aA2 = vmin3(aA2, vmin3(csel(m0,va.x,S), csel(m1,va.y,S), csel(m2,va.z,S)), csel(m3,va.w,S));
                aB2 = vmin3(aB2, vmin3(csel(m0,vb.x,S), csel(m1,vb.y,S), csel(m2,vb.z,S)), csel(m3,vb.w,S));
            }
            {
                unsigned long long m0=mw3[c*4+0], m1=mw3[c*4+1], m2=mw3[c*4+2], m3=mw3[c*4+3];
                aA3 = vmin3(aA3, vmin3(csel(m0,va.x,S), csel(m1,va.y,S), csel(m2,va.z,S)), csel(m3,va.w,S));
                aB3 = vmin3(aB3, vmin3(csel(m0,vb.x,S), csel(m1,vb.y,S), csel(m2,vb.z,S)), csel(m3,vb.w,S));
            }
        }
        // branchless pair-merge: expose partner's needed value, one shfl
        float c0 = hi ? aA0 : aB0;  float p0 = __shfl_xor(c0, 32, 64);
        float c1 = hi ? aA1 : aB1;  float p1 = __shfl_xor(c1, 32, 64);
        float c2 = hi ? aA2 : aB2;  float p2 = __shfl_xor(c2, 32, 64);
        float c3 = hi ? aA3 : aB3;  float p3 = __shfl_xor(c3, 32, 64);
        float z0 = fminf(hi ? aB0 : aA0, p0);
        float z1 = fminf(hi ? aB1 : aA1, p1);
        float z2 = fminf(hi ? aB2 : aA2, p2);
        float z3 = fminf(hi ? aB3 : aA3, p3);
        #pragma unroll
        for (int d = 16; d; d >>= 1) {
            z0 = fminf(z0, __shfl_xor(z0, d, 64));
            z1 = fminf(z1, __shfl_xor(z1, d, 64));
            z2 = fminf(z2, __shfl_xor(z2, d, 64));
            z3 = fminf(z3, __shfl_xor(z3, d, 64));
        }
        if ((lane & 31) == 0) {
            float* ob = out + (bp * 2 + (lane >> 5)) * OUT_F;
            ob[o0] = z0; ob[o1] = z1; ob[o2] = z2; ob[o3] = z3;
        }
    } else {
        // t-conorm: max, offset/sentinel -1.0
        const float S = -1.0f;
        float aA0=S, aA1=S, aA2=S, aA3=S;
        float aB0=S, aB1=S, aB2=S, aB3=S;
        #pragma unroll
        for (int c = 0; c < 4; ++c) {
            float4 va = xA[c * 64 + lane];
            float4 vb = xB[c * 64 + lane];
            {
                unsigned long long m0=mw0[c*4+0], m1=mw0[c*4+1], m2=mw0[c*4+2], m3=mw0[c*4+3];
                aA0 = vmax3(aA0, vmax3(csel(m0,va.x,S), csel(m1,va.y,S), csel(m2,va.z,S)), csel(m3,va.w,S));
                aB0 = vmax3(aB0, vmax3(csel(m0,vb.x,S), csel(m1,vb.y,S), csel(m2,vb.z,S)), csel(m3,vb.w,S));
            }
            {
                unsigned long long m0=mw1[c*4+0], m1=mw1[c*4+1], m2=mw1[c*4+2], m3=mw1[c*4+3];
                aA1 = vmax3(aA1, vmax3(csel(m0,va.x,S), csel(m1,va.y,S), csel(m2,va.z,S)), csel(m3,va.w,S));
                aB1 = vmax3(aB1, vmax3(csel(m0,vb.x,S), csel(m1,vb.y,S), csel(m2,vb.z,S)), csel(m3,vb.w,S));
            }
            {
                unsigned long long m0=mw2[c*4+0], m1=mw2[c*4+1], m2=mw2[c*4+2], m3=mw2[c*4+3];
                aA2 = vmax3(aA2, vmax3(csel(m0,va.x,S), csel(m1,va.y,S), csel(m2,va.z,S)), csel(m3,va.w,S));
                aB2 = vmax3(aB2, vmax3(csel(m0,vb.x,S), csel(m1,vb.y,S), csel(m2,vb.z,S)), csel(m3,vb.w,S));
            }
            {
                unsigned long long m0=mw3[c*4+0], m1=mw3[c*4+1], m2=mw3[c*4+2], m3=mw3[c*4+3];
                aA3 = vmax3(aA3, vmax3(csel(m0,va.x,S), csel(m1,va.y,S), csel(m2,va.z,S)), csel(m3,va.w,S));
                aB3 = vmax3(aB3, vmax3(csel(m0,vb.x,S), csel(m1,vb.y,S), csel(m2,vb.z,S)), csel(m3,vb.w,S));
            }
        }
        float c0 = hi ? aA0 : aB0;  float p0 = __shfl_xor(c0, 32, 64);
        float c1 = hi ? aA1 : aB1;  float p1 = __shfl_xor(c1, 32, 64);
        float c2 = hi ? aA2 : aB2;  float p2 = __shfl_xor(c2, 32, 64);
        float c3 = hi ? aA3 : aB3;  float p3 = __shfl_xor(c3, 32, 64);
        float z0 = fmaxf(hi ? aB0 : aA0, p0);
        float z1 = fmaxf(hi ? aB1 : aA1, p1);
        float z2 = fmaxf(hi ? aB2 : aA2, p2);
        float z3 = fmaxf(hi ? aB3 : aA3, p3);
        #pragma unroll
        for (int d = 16; d; d >>= 1) {
            z0 = fmaxf(z0, __shfl_xor(z0, d, 64));
            z1 = fmaxf(z1, __shfl_xor(z1, d, 64));
            z2 = fmaxf(z2, __shfl_xor(z2, d, 64));
            z3 = fmaxf(z3, __shfl_xor(z3, d, 64));
        }
        if ((lane & 31) == 0) {
            float* ob = out + (bp * 2 + (lane >> 5)) * OUT_F;
            ob[o0] = z0; ob[o1] = z1; ob[o2] = z2; ob[o3] = z3;
        }
    }
}

extern "C" void kernel_launch(void* const* d_in, const int* in_sizes, int n_in,
                              void* d_out, int out_size, void* d_ws, size_t ws_size,
                              hipStream_t stream) {
    const float* x   = (const float*)d_in[0];  // [BATCH, IN_F]
    const float* etc = (const float*)d_in[1];  // [OUT_F, IN_F, 2]
    const float* un  = (const float*)d_in[2];  // [OUT_F, IN_F, 2]
    float* out = (float*)d_out;                // [BATCH, OUT_F]
    unsigned long long* mask_t = (unsigned long long*)d_ws;  // 64 KB

    // Kernel A: one block per (o, 256-i chunk)
    hipLaunchKernelGGL(mask_kernel, dim3(OUT_F * 4), dim3(256), 0, stream,
                       etc, un, mask_t);
    // Kernel B: 16384 wave-tasks (2 b-rows x 4 same-parity o's), 4 waves/block
    hipLaunchKernelGGL(reduce_kernel, dim3(BATCH * OUT_F / 8 / 4), dim3(256), 0, stream,
                       x, mask_t, out);
}